// Round 17
// baseline (888.926 us; speedup 1.0000x reference)
//
#include <hip/hip_runtime.h>
#include <math.h>

#define GLB_PTR(x) ((const __attribute__((address_space(1))) void*)(x))
#define LDS_PTR(x) ((__attribute__((address_space(3))) void*)(x))

typedef __bf16 bf16x8 __attribute__((ext_vector_type(8)));
typedef float  f32x4  __attribute__((ext_vector_type(4)));

// Sizes: B=512, S=8, U=512, D=32, G=8, DIM_IN=4096, DAG=2048
// out layout: att[512*16384] | ga[512*2048] | w[512^3] | outputs[512*16384]
// No-max softmax: scores kernel stores p = exp(s) (masked -> 0) into the w
// region and accumulates L_g; stats cell (b,u) floats [0..7] = 1/(8 L_g).
// emit kernel: w = p * IL_g + PV accumulation; overwrites stats cells.

// ---------------- K1/K2: per-split fp32 GEMM (64x64 tile, Kstep 16) ----------------
__global__ __launch_bounds__(256) void gemm_split(
    const float* __restrict__ A, int lda, int Ksz,
    const float* __restrict__ Bw, int NS,
    const float* __restrict__ bias,
    float* __restrict__ C, int ldc)
{
  const int n0 = blockIdx.x * 64;
  const int b0 = blockIdx.y * 64;
  const int s  = n0 / NS;
  const float* Bp = Bw + (size_t)s * Ksz * NS;
  const int nloc0 = n0 - s * NS;
  const int acol0 = s * Ksz;

  __shared__ float As[16][64];
  __shared__ float Bs[16][64];

  const int t  = threadIdx.x;
  const int tb = t & 15, tn = t >> 4;
  float acc[4][4] = {};

  for (int k0 = 0; k0 < Ksz; k0 += 16) {
    {
      int r = t & 63, g = t >> 6;
      float4 v = *reinterpret_cast<const float4*>(
          A + (size_t)(b0 + r) * lda + acol0 + k0 + 4 * g);
      As[4*g+0][r] = v.x; As[4*g+1][r] = v.y; As[4*g+2][r] = v.z; As[4*g+3][r] = v.w;
    }
    {
      int kk = t >> 4, n4 = t & 15;
      float4 v = *reinterpret_cast<const float4*>(
          Bp + (size_t)(k0 + kk) * NS + nloc0 + 4 * n4);
      *reinterpret_cast<float4*>(&Bs[kk][4*n4]) = v;
    }
    __syncthreads();
#pragma unroll
    for (int k = 0; k < 16; ++k) {
      float4 a4 = *reinterpret_cast<const float4*>(&As[k][4*tb]);
      float4 b4 = *reinterpret_cast<const float4*>(&Bs[k][4*tn]);
      float av[4] = {a4.x, a4.y, a4.z, a4.w};
      float bv[4] = {b4.x, b4.y, b4.z, b4.w};
#pragma unroll
      for (int i = 0; i < 4; ++i)
#pragma unroll
        for (int j = 0; j < 4; ++j)
          acc[i][j] = fmaf(av[i], bv[j], acc[i][j]);
    }
    __syncthreads();
  }
#pragma unroll
  for (int i = 0; i < 4; ++i) {
    int row = b0 + 4*tb + i;
    int col = n0 + 4*tn;
    float4 o;
    o.x = acc[i][0] + bias[col + 0];
    o.y = acc[i][1] + bias[col + 1];
    o.z = acc[i][2] + bias[col + 2];
    o.w = acc[i][3] + bias[col + 3];
    *reinterpret_cast<float4*>(C + (size_t)row * ldc + col) = o;
  }
}

// ---------------- K3a (MFMA v5): p = exp(masked score) + group sums ----------------
// (unchanged from round 13 -- validated at ~370 us)
__global__ __launch_bounds__(256) void scores_mfma_v5(
    const float* __restrict__ att,   // [512][512][32]
    const float* __restrict__ ma,    // [512][512][32]
    const float* __restrict__ rnd,   // [512][512][512]
    const float* __restrict__ temp,  // [512]
    float* __restrict__ wout,        // [512][512][512] <- p values
    float* __restrict__ stats)       // outs region base
{
  __shared__ float MaL[2048 * 4];    // 32 KB staged ma chunk (f4 slots)
  __shared__ float tr[256 * 17];     // 17 KB C transpose
  const int b0 = blockIdx.x * 16;
  const int u0 = blockIdx.y * 16;
  const int t  = threadIdx.x;
  const int w  = t >> 6, l = t & 63;
  const int lm = l & 15, kb = l >> 4;      // MFMA decode: m / k-block
  const int eu = t & 15, eb = t >> 4;      // emit decode: u / b
  const int gbe = b0 + eb;

  const float tmp = temp[u0 + eu];         // emit's single temperature

  // A-fragments (att) for the wave's 4 u's, split hi/lo bf16, loaded once
  bf16x8 Ahi[4], Alo[4];
#pragma unroll
  for (int q = 0; q < 4; ++q) {
    const float* ap = att + (size_t)(b0 + lm) * 16384
                    + (size_t)(u0 + 4 * w + q) * 32 + kb * 8;
    float4 a0 = *reinterpret_cast<const float4*>(ap);
    float4 a1 = *reinterpret_cast<const float4*>(ap + 4);
    float af[8] = {a0.x, a0.y, a0.z, a0.w, a1.x, a1.y, a1.z, a1.w};
#pragma unroll
    for (int j = 0; j < 8; ++j) {
      __bf16 h = (__bf16)af[j];
      Ahi[q][j] = h;
      Alo[q][j] = (__bf16)(af[j] - (float)h);
    }
  }

  // staging source offsets: slot s = k*256 + t holds ma(m=s>>7, u=(s>>3)&15,
  // d-quad = (s&7) ^ (m&7)) of the current chunk
  int off[8];
#pragma unroll
  for (int k = 0; k < 8; ++k) {
    int s = k * 256 + t;
    int mm = s >> 7, uu = (s >> 3) & 15, d4s = s & 7;
    off[k] = mm * 16384 + (u0 + uu) * 32 + ((d4s ^ (mm & 7)) << 2);
  }

  float Ls[8];
#pragma unroll
  for (int g = 0; g < 8; ++g) Ls[g] = 0.f;

  const float* rbase = rnd  + (size_t)gbe * 262144 + u0 + eu;   // + m*512
  float*       wbase = wout + (size_t)gbe * 262144 + u0 + eu;

  // prologue: stage chunk 0 + rnd chunk 0
#pragma unroll
  for (int k = 0; k < 8; ++k)
    __builtin_amdgcn_global_load_lds(GLB_PTR(ma + (size_t)off[k]),
                                     LDS_PTR(&MaL[(k * 256 + w * 64) * 4]), 16, 0, 0);
  float rc[16], rn[16];
#pragma unroll
  for (int j = 0; j < 16; ++j) rc[j] = rbase[(size_t)j * 512];

#pragma unroll 1
  for (int c = 0; c < 32; ++c) {
    const int m0 = c * 16;
    __syncthreads();                 // A: MaL(c) drained; tr(c-1) consumed

    // ---- MFMA role: 4 u's of this wave ----
#pragma unroll
    for (int q = 0; q < 4; ++q) {
      const int uq = 4 * w + q;
      const int s0 = (lm << 7) + (uq << 3) + ((2 * kb)     ^ (lm & 7));
      const int s1 = (lm << 7) + (uq << 3) + ((2 * kb + 1) ^ (lm & 7));
      float4 g0 = *reinterpret_cast<const float4*>(&MaL[s0 * 4]);
      float4 g1 = *reinterpret_cast<const float4*>(&MaL[s1 * 4]);
      float bf[8] = {g0.x, g0.y, g0.z, g0.w, g1.x, g1.y, g1.z, g1.w};
      bf16x8 Bhi, Blo;
#pragma unroll
      for (int j = 0; j < 8; ++j) {
        __bf16 h = (__bf16)bf[j];
        Bhi[j] = h;
        Blo[j] = (__bf16)(bf[j] - (float)h);
      }
      f32x4 a = {0.f, 0.f, 0.f, 0.f};
      a = __builtin_amdgcn_mfma_f32_16x16x32_bf16(Ahi[q], Blo, a, 0, 0, 0);
      a = __builtin_amdgcn_mfma_f32_16x16x32_bf16(Alo[q], Bhi, a, 0, 0, 0);
      a = __builtin_amdgcn_mfma_f32_16x16x32_bf16(Ahi[q], Bhi, a, 0, 0, 0);
      // C: b = kb*4+i, m = lm  ->  row = b*16 + m, swizzled u slot
#pragma unroll
      for (int i = 0; i < 4; ++i) {
        const int row = (kb * 4 + i) * 16 + lm;
        tr[row * 17 + (uq ^ ((row >> 6) << 2))] = a[i];
      }
    }
    __syncthreads();                 // B: tr(c) visible; MaL(c) reads done

    // ---- issue chunk c+1 staging + rnd(c+1): covered by emit(c) ----
    if (c < 31) {
#pragma unroll
      for (int k = 0; k < 8; ++k)
        __builtin_amdgcn_global_load_lds(
            GLB_PTR(ma + (size_t)off[k] + (size_t)(m0 + 16) * 16384),
            LDS_PTR(&MaL[(k * 256 + w * 64) * 4]), 16, 0, 0);
#pragma unroll
      for (int j = 0; j < 16; ++j)
        rn[j] = rbase[(size_t)(m0 + 16 + j) * 512];
    }

    // ---- emit role: thread (u = eu, b = eb), 16 m, coalesced IO ----
    const int swz = (eb >> 2) << 2;  // (row>>6) for row = eb*16 + m
    const float* trow = &tr[(eb * 16) * 17 + (eu ^ swz)];
#pragma unroll
    for (int j = 0; j < 16; ++j) {
      const int gm = m0 + j;
      float p;
      if ((rc[j] < 0.1f) | (gm == gbe)) p = 0.f;
      else                              p = __expf(trow[j * 17] * tmp);
      wbase[(size_t)gm * 512] = p;
      Ls[j & 7] += p;
    }
#pragma unroll
    for (int j = 0; j < 16; ++j) rc[j] = rn[j];
  }

  // ---- stats: thread owns (b,u) completely -- direct write, no merge ----
  {
    float* cell = stats + ((size_t)gbe * 512 + u0 + eu) * 32;
#pragma unroll
    for (int g = 0; g < 8; ++g) cell[g] = 1.0f / (8.0f * Ls[g]);
  }
}

// ---------------- K3b v6: v5 structure + v4's conflict-free E layout ----------
// Block 8b x 16u, grid 2048 XCD-chunked, LDS 24.7 KB -> 6 blocks/CU.
// Phase A thread = (uq = t&3, am = (t>>2)&7, bh = t>>5): f4-over-u w IO
// (1 KB per wave instruction). E back to pad 17 + SCALAR writes (v4-proven;
// odd pad puts u-entropy into banks; pad-12 f4 rows were the v5 regression:
// 6.3e7 conflicts). Phase B = v4-identical read patterns.
__global__ __launch_bounds__(256) void emit_outputs_v6(
    const float* __restrict__ mo,    // [512][512][32]
    float* __restrict__ w,           // in: p values, out: final w
    float* __restrict__ outs)        // in: stats cells (IL), out: outputs
{
  __shared__ float MoL[8 * 16 * 32];   // 16 KB
  __shared__ float E[8 * 16 * 17];     // 8.7 KB, pad 17 (odd -> bank entropy)
  const int bid = blockIdx.x;
  const int id  = (bid & 7) * 256 + (bid >> 3);   // 2048 = 8 x 256, bijective
  const int b0  = (id & 63) * 8;                  // b-tile fast within XCD
  const int u0  = (id >> 6) * 16;
  const int t   = threadIdx.x;
  // phase A ids
  const int uq = t & 3, am = (t >> 2) & 7, bh = t >> 5;
  // phase B ids
  const int pu = t >> 4, bh2 = (t >> 3) & 1, dh = t & 7;

  // IL for (b = b0+bh, u = u0+4uq+e, g = am)
  float Sreg[4];
#pragma unroll
  for (int e = 0; e < 4; ++e)
    Sreg[e] = outs[((size_t)(b0 + bh) * 512 + u0 + 4 * uq + e) * 32 + am];

  float4 acc[4];
#pragma unroll
  for (int i = 0; i < 4; ++i) acc[i] = make_float4(0.f, 0.f, 0.f, 0.f);

  // w pointer for this thread's (b, m, u-quad): + mc*512 per chunk
  float* wb = w + (size_t)(b0 + bh) * 262144 + (size_t)am * 512 + u0 + 4 * uq;

  // mo staging: slab 8m x 16u x 32d, source-swizzled d-quads
  const float* msrc0;  const float* msrc1;  const float* msrc2;  const float* msrc3;
  int loff0, loff1, loff2, loff3;
  {
    int P, mm, uu, dq;
    P = t;          mm = P >> 7; uu = (P >> 3) & 15; dq = P & 7;
    msrc0 = mo + (size_t)mm * 16384 + (size_t)(u0 + uu) * 32 + (dq ^ (uu & 7)) * 4;
    loff0 = P * 4;
    P = 256 + t;    mm = P >> 7; uu = (P >> 3) & 15; dq = P & 7;
    msrc1 = mo + (size_t)mm * 16384 + (size_t)(u0 + uu) * 32 + (dq ^ (uu & 7)) * 4;
    loff1 = P * 4;
    P = 512 + t;    mm = P >> 7; uu = (P >> 3) & 15; dq = P & 7;
    msrc2 = mo + (size_t)mm * 16384 + (size_t)(u0 + uu) * 32 + (dq ^ (uu & 7)) * 4;
    loff2 = P * 4;
    P = 768 + t;    mm = P >> 7; uu = (P >> 3) & 15; dq = P & 7;
    msrc3 = mo + (size_t)mm * 16384 + (size_t)(u0 + uu) * 32 + (dq ^ (uu & 7)) * 4;
    loff3 = P * 4;
  }

  // prologue: chunk 0 into regs
  float4 wpre, smo0, smo1, smo2, smo3;
  wpre = *reinterpret_cast<const float4*>(wb);
  smo0 = *reinterpret_cast<const float4*>(msrc0);
  smo1 = *reinterpret_cast<const float4*>(msrc1);
  smo2 = *reinterpret_cast<const float4*>(msrc2);
  smo3 = *reinterpret_cast<const float4*>(msrc3);

#pragma unroll 1
  for (int c = 0; c < 64; ++c) {
    const int mc = c * 8;
    if (c) __syncthreads();            // phase B of c-1 done with E/MoL

    // ---- phase A: v = p*IL -> w (f4) + E (scalar, pad 17); staged mo ----
    {
      float4 vv;
      vv.x = wpre.x * Sreg[0];
      vv.y = wpre.y * Sreg[1];
      vv.z = wpre.z * Sreg[2];
      vv.w = wpre.w * Sreg[3];
      *reinterpret_cast<float4*>(wb + (size_t)mc * 512) = vv;
      E[(am * 16 + 4 * uq + 0) * 17 + bh] = vv.x;
      E[(am * 16 + 4 * uq + 1) * 17 + bh] = vv.y;
      E[(am * 16 + 4 * uq + 2) * 17 + bh] = vv.z;
      E[(am * 16 + 4 * uq + 3) * 17 + bh] = vv.w;
    }
    *reinterpret_cast<float4*>(&MoL[loff0]) = smo0;
    *reinterpret_cast<float4*>(&MoL[loff1]) = smo1;
    *reinterpret_cast<float4*>(&MoL[loff2]) = smo2;
    *reinterpret_cast<float4*>(&MoL[loff3]) = smo3;
    __syncthreads();                   // E + MoL ready

    // ---- issue prefetch for chunk c+1 (covered by phase B) ----
    if (c < 63) {
      wpre = *reinterpret_cast<const float4*>(wb + (size_t)(mc + 8) * 512);
      const size_t moff = (size_t)(mc + 8) * 16384;
      smo0 = *reinterpret_cast<const float4*>(msrc0 + moff);
      smo1 = *reinterpret_cast<const float4*>(msrc1 + moff);
      smo2 = *reinterpret_cast<const float4*>(msrc2 + moff);
      smo3 = *reinterpret_cast<const float4*>(msrc3 + moff);
    }

    // ---- phase B: acc[4b](f4 d) += E[m][pu][b-quad bh2] * Mo[m][pu][dq dh] ----
#pragma unroll
    for (int m = 0; m < 8; ++m) {
      float4 ef = *reinterpret_cast<const float4*>(&E[(m * 16 + pu) * 17 + 4 * bh2]);
      float4 v  = *reinterpret_cast<const float4*>(
          &MoL[(m * 16 + pu) * 32 + ((dh ^ (pu & 7)) * 4)]);
      acc[0].x = fmaf(ef.x, v.x, acc[0].x);
      acc[0].y = fmaf(ef.x, v.y, acc[0].y);
      acc[0].z = fmaf(ef.x, v.z, acc[0].z);
      acc[0].w = fmaf(ef.x, v.w, acc[0].w);
      acc[1].x = fmaf(ef.y, v.x, acc[1].x);
      acc[1].y = fmaf(ef.y, v.y, acc[1].y);
      acc[1].z = fmaf(ef.y, v.z, acc[1].z);
      acc[1].w = fmaf(ef.y, v.w, acc[1].w);
      acc[2].x = fmaf(ef.z, v.x, acc[2].x);
      acc[2].y = fmaf(ef.z, v.y, acc[2].y);
      acc[2].z = fmaf(ef.z, v.z, acc[2].z);
      acc[2].w = fmaf(ef.z, v.w, acc[2].w);
      acc[3].x = fmaf(ef.w, v.x, acc[3].x);
      acc[3].y = fmaf(ef.w, v.y, acc[3].y);
      acc[3].z = fmaf(ef.w, v.z, acc[3].z);
      acc[3].w = fmaf(ef.w, v.w, acc[3].w);
    }
  }

  // epilogue: overwrite stats cells with final outputs
#pragma unroll
  for (int i = 0; i < 4; ++i) {
    float* dst = outs + ((size_t)(b0 + 4 * bh2 + i) * 512 + u0 + pu) * 32 + dh * 4;
    *reinterpret_cast<float4*>(dst) = acc[i];
  }
}

extern "C" void kernel_launch(void* const* d_in, const int* in_sizes, int n_in,
                              void* d_out, int out_size, void* d_ws, size_t ws_size,
                              hipStream_t stream) {
  const float* x    = (const float*)d_in[0];   // [512][4096]
  const float* ma   = (const float*)d_in[1];   // [512][512][32]
  const float* mo   = (const float*)d_in[2];   // [512][512][32]
  const float* rnd  = (const float*)d_in[3];   // [512][512][512]
  const float* w1   = (const float*)d_in[4];   // [8][512][256]
  const float* b1   = (const float*)d_in[5];   // [8][256]
  const float* w2   = (const float*)d_in[6];   // [8][256][2048]
  const float* b2   = (const float*)d_in[7];   // [8][2048]
  const float* temp = (const float*)d_in[8];   // [512]

  float* out  = (float*)d_out;
  float* att  = out;                  // 8388608
  float* ga   = out + 8388608;        // 1048576
  float* wbuf = out + 9437184;        // 134217728
  float* outs = out + 143654912;      // 8388608

  gemm_split<<<dim3(32, 8), 256, 0, stream>>>(x, 4096, 512, w1, 256, b1, ga, 2048);
  gemm_split<<<dim3(256, 8), 256, 0, stream>>>(ga, 2048, 256, w2, 2048, b2, att, 16384);
  scores_mfma_v5<<<dim3(32, 32), 256, 0, stream>>>(att, ma, rnd, temp, wbuf, outs);
  emit_outputs_v6<<<dim3(2048), 256, 0, stream>>>(mo, wbuf, outs);
}

// Round 18
// 812.854 us; speedup vs baseline: 1.0936x; 1.0936x over previous
//
#include <hip/hip_runtime.h>
#include <math.h>

#define GLB_PTR(x) ((const __attribute__((address_space(1))) void*)(x))
#define LDS_PTR(x) ((__attribute__((address_space(3))) void*)(x))

typedef __bf16 bf16x8 __attribute__((ext_vector_type(8)));
typedef float  f32x4  __attribute__((ext_vector_type(4)));

// Sizes: B=512, S=8, U=512, D=32, G=8, DIM_IN=4096, DAG=2048
// out layout: att[512*16384] | ga[512*2048] | w[512^3] | outputs[512*16384]
// No-max softmax. p is carried scores->emit either as bf16 in d_ws (saves
// 512 MB HBM; numerics: 2^-9 rel err << thresholds) or, if ws is too small,
// as fp32 in the w region (exactly the round-13 champion path).

// ---------------- K1/K2: per-split fp32 GEMM (64x64 tile, Kstep 16) ----------------
__global__ __launch_bounds__(256) void gemm_split(
    const float* __restrict__ A, int lda, int Ksz,
    const float* __restrict__ Bw, int NS,
    const float* __restrict__ bias,
    float* __restrict__ C, int ldc)
{
  const int n0 = blockIdx.x * 64;
  const int b0 = blockIdx.y * 64;
  const int s  = n0 / NS;
  const float* Bp = Bw + (size_t)s * Ksz * NS;
  const int nloc0 = n0 - s * NS;
  const int acol0 = s * Ksz;

  __shared__ float As[16][64];
  __shared__ float Bs[16][64];

  const int t  = threadIdx.x;
  const int tb = t & 15, tn = t >> 4;
  float acc[4][4] = {};

  for (int k0 = 0; k0 < Ksz; k0 += 16) {
    {
      int r = t & 63, g = t >> 6;
      float4 v = *reinterpret_cast<const float4*>(
          A + (size_t)(b0 + r) * lda + acol0 + k0 + 4 * g);
      As[4*g+0][r] = v.x; As[4*g+1][r] = v.y; As[4*g+2][r] = v.z; As[4*g+3][r] = v.w;
    }
    {
      int kk = t >> 4, n4 = t & 15;
      float4 v = *reinterpret_cast<const float4*>(
          Bp + (size_t)(k0 + kk) * NS + nloc0 + 4 * n4);
      *reinterpret_cast<float4*>(&Bs[kk][4*n4]) = v;
    }
    __syncthreads();
#pragma unroll
    for (int k = 0; k < 16; ++k) {
      float4 a4 = *reinterpret_cast<const float4*>(&As[k][4*tb]);
      float4 b4 = *reinterpret_cast<const float4*>(&Bs[k][4*tn]);
      float av[4] = {a4.x, a4.y, a4.z, a4.w};
      float bv[4] = {b4.x, b4.y, b4.z, b4.w};
#pragma unroll
      for (int i = 0; i < 4; ++i)
#pragma unroll
        for (int j = 0; j < 4; ++j)
          acc[i][j] = fmaf(av[i], bv[j], acc[i][j]);
    }
    __syncthreads();
  }
#pragma unroll
  for (int i = 0; i < 4; ++i) {
    int row = b0 + 4*tb + i;
    int col = n0 + 4*tn;
    float4 o;
    o.x = acc[i][0] + bias[col + 0];
    o.y = acc[i][1] + bias[col + 1];
    o.z = acc[i][2] + bias[col + 2];
    o.w = acc[i][3] + bias[col + 3];
    *reinterpret_cast<float4*>(C + (size_t)row * ldc + col) = o;
  }
}

// ---------------- K3a (MFMA v5): p = exp(masked score) + group sums ----------------
// Round-13 structure verbatim; PT = p carrier type (float -> w region in
// place, or __bf16 -> d_ws).
template <typename PT>
__global__ __launch_bounds__(256) void scores_mfma_v5(
    const float* __restrict__ att,   // [512][512][32]
    const float* __restrict__ ma,    // [512][512][32]
    const float* __restrict__ rnd,   // [512][512][512]
    const float* __restrict__ temp,  // [512]
    PT* __restrict__ pout,           // [512][512][512] p values
    float* __restrict__ stats)       // outs region base
{
  __shared__ float MaL[2048 * 4];    // 32 KB staged ma chunk (f4 slots)
  __shared__ float tr[256 * 17];     // 17 KB C transpose
  const int b0 = blockIdx.x * 16;
  const int u0 = blockIdx.y * 16;
  const int t  = threadIdx.x;
  const int w  = t >> 6, l = t & 63;
  const int lm = l & 15, kb = l >> 4;      // MFMA decode: m / k-block
  const int eu = t & 15, eb = t >> 4;      // emit decode: u / b
  const int gbe = b0 + eb;

  const float tmp = temp[u0 + eu];         // emit's single temperature

  // A-fragments (att) for the wave's 4 u's, split hi/lo bf16, loaded once
  bf16x8 Ahi[4], Alo[4];
#pragma unroll
  for (int q = 0; q < 4; ++q) {
    const float* ap = att + (size_t)(b0 + lm) * 16384
                    + (size_t)(u0 + 4 * w + q) * 32 + kb * 8;
    float4 a0 = *reinterpret_cast<const float4*>(ap);
    float4 a1 = *reinterpret_cast<const float4*>(ap + 4);
    float af[8] = {a0.x, a0.y, a0.z, a0.w, a1.x, a1.y, a1.z, a1.w};
#pragma unroll
    for (int j = 0; j < 8; ++j) {
      __bf16 h = (__bf16)af[j];
      Ahi[q][j] = h;
      Alo[q][j] = (__bf16)(af[j] - (float)h);
    }
  }

  // staging source offsets: slot s = k*256 + t holds ma(m=s>>7, u=(s>>3)&15,
  // d-quad = (s&7) ^ (m&7)) of the current chunk
  int off[8];
#pragma unroll
  for (int k = 0; k < 8; ++k) {
    int s = k * 256 + t;
    int mm = s >> 7, uu = (s >> 3) & 15, d4s = s & 7;
    off[k] = mm * 16384 + (u0 + uu) * 32 + ((d4s ^ (mm & 7)) << 2);
  }

  float Ls[8];
#pragma unroll
  for (int g = 0; g < 8; ++g) Ls[g] = 0.f;

  const float* rbase = rnd + (size_t)gbe * 262144 + u0 + eu;   // + m*512
  PT*          pbase = pout + (size_t)gbe * 262144 + u0 + eu;

  // prologue: stage chunk 0 + rnd chunk 0
#pragma unroll
  for (int k = 0; k < 8; ++k)
    __builtin_amdgcn_global_load_lds(GLB_PTR(ma + (size_t)off[k]),
                                     LDS_PTR(&MaL[(k * 256 + w * 64) * 4]), 16, 0, 0);
  float rc[16], rn[16];
#pragma unroll
  for (int j = 0; j < 16; ++j) rc[j] = rbase[(size_t)j * 512];

#pragma unroll 1
  for (int c = 0; c < 32; ++c) {
    const int m0 = c * 16;
    __syncthreads();                 // A: MaL(c) drained; tr(c-1) consumed

    // ---- MFMA role: 4 u's of this wave ----
#pragma unroll
    for (int q = 0; q < 4; ++q) {
      const int uq = 4 * w + q;
      const int s0 = (lm << 7) + (uq << 3) + ((2 * kb)     ^ (lm & 7));
      const int s1 = (lm << 7) + (uq << 3) + ((2 * kb + 1) ^ (lm & 7));
      float4 g0 = *reinterpret_cast<const float4*>(&MaL[s0 * 4]);
      float4 g1 = *reinterpret_cast<const float4*>(&MaL[s1 * 4]);
      float bf[8] = {g0.x, g0.y, g0.z, g0.w, g1.x, g1.y, g1.z, g1.w};
      bf16x8 Bhi, Blo;
#pragma unroll
      for (int j = 0; j < 8; ++j) {
        __bf16 h = (__bf16)bf[j];
        Bhi[j] = h;
        Blo[j] = (__bf16)(bf[j] - (float)h);
      }
      f32x4 a = {0.f, 0.f, 0.f, 0.f};
      a = __builtin_amdgcn_mfma_f32_16x16x32_bf16(Ahi[q], Blo, a, 0, 0, 0);
      a = __builtin_amdgcn_mfma_f32_16x16x32_bf16(Alo[q], Bhi, a, 0, 0, 0);
      a = __builtin_amdgcn_mfma_f32_16x16x32_bf16(Ahi[q], Bhi, a, 0, 0, 0);
      // C: b = kb*4+i, m = lm  ->  row = b*16 + m, swizzled u slot
#pragma unroll
      for (int i = 0; i < 4; ++i) {
        const int row = (kb * 4 + i) * 16 + lm;
        tr[row * 17 + (uq ^ ((row >> 6) << 2))] = a[i];
      }
    }
    __syncthreads();                 // B: tr(c) visible; MaL(c) reads done

    // ---- issue chunk c+1 staging + rnd(c+1): covered by emit(c) ----
    if (c < 31) {
#pragma unroll
      for (int k = 0; k < 8; ++k)
        __builtin_amdgcn_global_load_lds(
            GLB_PTR(ma + (size_t)off[k] + (size_t)(m0 + 16) * 16384),
            LDS_PTR(&MaL[(k * 256 + w * 64) * 4]), 16, 0, 0);
#pragma unroll
      for (int j = 0; j < 16; ++j)
        rn[j] = rbase[(size_t)(m0 + 16 + j) * 512];
    }

    // ---- emit role: thread (u = eu, b = eb), 16 m, coalesced IO ----
    const int swz = (eb >> 2) << 2;  // (row>>6) for row = eb*16 + m
    const float* trow = &tr[(eb * 16) * 17 + (eu ^ swz)];
#pragma unroll
    for (int j = 0; j < 16; ++j) {
      const int gm = m0 + j;
      float p;
      if ((rc[j] < 0.1f) | (gm == gbe)) p = 0.f;
      else                              p = __expf(trow[j * 17] * tmp);
      pbase[(size_t)gm * 512] = (PT)p;
      Ls[j & 7] += p;
    }
#pragma unroll
    for (int j = 0; j < 16; ++j) rc[j] = rn[j];
  }

  // ---- stats: thread owns (b,u) completely -- direct write, no merge ----
  {
    float* cell = stats + ((size_t)gbe * 512 + u0 + eu) * 32;
#pragma unroll
    for (int g = 0; g < 8; ++g) cell[g] = 1.0f / (8.0f * Ls[g]);
  }
}

// ---------------- K3b v4: w = p*IL + outputs, u-fastest phase A keying ----------
// Round-13 structure verbatim; PT = p carrier type (reads pin, writes fp32 w).
template <typename PT>
__global__ __launch_bounds__(256) void emit_outputs_v4(
    const float* __restrict__ mo,    // [512][512][32]
    const PT* __restrict__ pin,      // p values
    float* __restrict__ wout,        // final w (fp32)
    float* __restrict__ outs)        // in: stats cells (IL), out: outputs
{
  __shared__ float MoL[8 * 16 * 32];
  __shared__ float E[8 * 16 * 17];
  const int u0 = blockIdx.x * 16;
  const int b0 = blockIdx.y * 16;
  const int t  = threadIdx.x;
  // phase A ids: u-fastest
  const int eu = t & 15, gg = t >> 4;
  const int ma_ = gg & 7, bpar = gg >> 3;          // m (== group), b parity
  // phase B ids
  const int pu = t >> 4, bq = (t >> 2) & 3, dh = t & 3;

  // IL for the 8 owned b's at fixed (u = eu, g = ma_)
  float Sreg[8];
#pragma unroll
  for (int k = 0; k < 8; ++k)
    Sreg[k] = outs[((size_t)(b0 + bpar + 2 * k) * 512 + u0 + eu) * 32 + ma_];

  float4 acc[4][2];
#pragma unroll
  for (int i = 0; i < 4; ++i) {
    acc[i][0] = make_float4(0.f, 0.f, 0.f, 0.f);
    acc[i][1] = make_float4(0.f, 0.f, 0.f, 0.f);
  }

  // p/w cell pointers: cell_k = [b0+bpar+2k][m = mc+ma_][u0+eu]
  const PT* pb = pin  + (size_t)(b0 + bpar) * 262144 + (size_t)ma_ * 512 + u0 + eu;
  float*    wf = wout + (size_t)(b0 + bpar) * 262144 + (size_t)ma_ * 512 + u0 + eu;

  const float* msrc0;  const float* msrc1;  const float* msrc2;  const float* msrc3;
  int loff0, loff1, loff2, loff3;
  {
    int P, mm, uu, dq;
    P = t;          mm = P >> 7; uu = (P >> 3) & 15; dq = P & 7;
    msrc0 = mo + (size_t)mm * 16384 + (size_t)(u0 + uu) * 32 + (dq ^ (uu & 7)) * 4;
    loff0 = P * 4;
    P = 256 + t;    mm = P >> 7; uu = (P >> 3) & 15; dq = P & 7;
    msrc1 = mo + (size_t)mm * 16384 + (size_t)(u0 + uu) * 32 + (dq ^ (uu & 7)) * 4;
    loff1 = P * 4;
    P = 512 + t;    mm = P >> 7; uu = (P >> 3) & 15; dq = P & 7;
    msrc2 = mo + (size_t)mm * 16384 + (size_t)(u0 + uu) * 32 + (dq ^ (uu & 7)) * 4;
    loff2 = P * 4;
    P = 768 + t;    mm = P >> 7; uu = (P >> 3) & 15; dq = P & 7;
    msrc3 = mo + (size_t)mm * 16384 + (size_t)(u0 + uu) * 32 + (dq ^ (uu & 7)) * 4;
    loff3 = P * 4;
  }

  // prologue: chunk 0 into regs
  float wpre[8];
  float4 smo0, smo1, smo2, smo3;
  {
#pragma unroll
    for (int k = 0; k < 8; ++k)
      wpre[k] = (float)pb[(size_t)(2 * k) * 262144];
    smo0 = *reinterpret_cast<const float4*>(msrc0);
    smo1 = *reinterpret_cast<const float4*>(msrc1);
    smo2 = *reinterpret_cast<const float4*>(msrc2);
    smo3 = *reinterpret_cast<const float4*>(msrc3);
  }

#pragma unroll 1
  for (int c = 0; c < 64; ++c) {
    const int mc = c * 8;
    if (c) __syncthreads();            // phase B of c-1 done with E/MoL

    // ---- phase A: v = p*IL -> w writeback + E; ds_write staged mo ----
    {
      float* wp = wf + (size_t)mc * 512;
#pragma unroll
      for (int k = 0; k < 8; ++k) {
        float v = wpre[k] * Sreg[k];
        wp[(size_t)(2 * k) * 262144] = v;
        E[(ma_ * 16 + eu) * 17 + bpar + 2 * k] = v;
      }
    }
    *reinterpret_cast<float4*>(&MoL[loff0]) = smo0;
    *reinterpret_cast<float4*>(&MoL[loff1]) = smo1;
    *reinterpret_cast<float4*>(&MoL[loff2]) = smo2;
    *reinterpret_cast<float4*>(&MoL[loff3]) = smo3;
    __syncthreads();                   // E + MoL ready

    // ---- issue prefetch for chunk c+1 ----
    if (c < 63) {
      const PT* pp = pb + (size_t)(mc + 8) * 512;
#pragma unroll
      for (int k = 0; k < 8; ++k)
        wpre[k] = (float)pp[(size_t)(2 * k) * 262144];
      const size_t moff = (size_t)(mc + 8) * 16384;
      smo0 = *reinterpret_cast<const float4*>(msrc0 + moff);
      smo1 = *reinterpret_cast<const float4*>(msrc1 + moff);
      smo2 = *reinterpret_cast<const float4*>(msrc2 + moff);
      smo3 = *reinterpret_cast<const float4*>(msrc3 + moff);
    }

    // ---- phase B: acc[4b][8d] += E[m][pu][4b] * Mo[m][pu][8d] ----
#pragma unroll
    for (int m = 0; m < 8; ++m) {
      float4 ef = *reinterpret_cast<const float4*>(&E[(m * 16 + pu) * 17 + 4 * bq]);
      float4 v0 = *reinterpret_cast<const float4*>(
          &MoL[(m * 16 + pu) * 32 + (((2 * dh) ^ (pu & 7)) * 4)]);
      float4 v1 = *reinterpret_cast<const float4*>(
          &MoL[(m * 16 + pu) * 32 + (((2 * dh + 1) ^ (pu & 7)) * 4)]);
      float es[4] = {ef.x, ef.y, ef.z, ef.w};
#pragma unroll
      for (int i = 0; i < 4; ++i) {
        acc[i][0].x = fmaf(es[i], v0.x, acc[i][0].x);
        acc[i][0].y = fmaf(es[i], v0.y, acc[i][0].y);
        acc[i][0].z = fmaf(es[i], v0.z, acc[i][0].z);
        acc[i][0].w = fmaf(es[i], v0.w, acc[i][0].w);
        acc[i][1].x = fmaf(es[i], v1.x, acc[i][1].x);
        acc[i][1].y = fmaf(es[i], v1.y, acc[i][1].y);
        acc[i][1].z = fmaf(es[i], v1.z, acc[i][1].z);
        acc[i][1].w = fmaf(es[i], v1.w, acc[i][1].w);
      }
    }
  }

  // epilogue: overwrite stats cells with final outputs
#pragma unroll
  for (int i = 0; i < 4; ++i) {
    float* dst = outs + ((size_t)(b0 + 4 * bq + i) * 512 + u0 + pu) * 32 + 8 * dh;
    *reinterpret_cast<float4*>(dst)     = acc[i][0];
    *reinterpret_cast<float4*>(dst + 4) = acc[i][1];
  }
}

extern "C" void kernel_launch(void* const* d_in, const int* in_sizes, int n_in,
                              void* d_out, int out_size, void* d_ws, size_t ws_size,
                              hipStream_t stream) {
  const float* x    = (const float*)d_in[0];   // [512][4096]
  const float* ma   = (const float*)d_in[1];   // [512][512][32]
  const float* mo   = (const float*)d_in[2];   // [512][512][32]
  const float* rnd  = (const float*)d_in[3];   // [512][512][512]
  const float* w1   = (const float*)d_in[4];   // [8][512][256]
  const float* b1   = (const float*)d_in[5];   // [8][256]
  const float* w2   = (const float*)d_in[6];   // [8][256][2048]
  const float* b2   = (const float*)d_in[7];   // [8][2048]
  const float* temp = (const float*)d_in[8];   // [512]

  float* out  = (float*)d_out;
  float* att  = out;                  // 8388608
  float* ga   = out + 8388608;        // 1048576
  float* wbuf = out + 9437184;        // 134217728
  float* outs = out + 143654912;      // 8388608

  gemm_split<<<dim3(32, 8), 256, 0, stream>>>(x, 4096, 512, w1, 256, b1, ga, 2048);
  gemm_split<<<dim3(256, 8), 256, 0, stream>>>(ga, 2048, 256, w2, 2048, b2, att, 16384);

  const size_t PBYTES = (size_t)512 * 512 * 512 * sizeof(__bf16);  // 256 MB
  if (ws_size >= PBYTES) {
    // bf16 p through workspace: saves 512 MB of HBM round-trip
    __bf16* pws = (__bf16*)d_ws;
    scores_mfma_v5<__bf16><<<dim3(32, 32), 256, 0, stream>>>(
        att, ma, rnd, temp, pws, outs);
    emit_outputs_v4<__bf16><<<dim3(32, 32), 256, 0, stream>>>(
        mo, pws, wbuf, outs);
  } else {
    // fallback: fp32 p in the w region, in place (round-13 champion path)
    scores_mfma_v5<float><<<dim3(32, 32), 256, 0, stream>>>(
        att, ma, rnd, temp, wbuf, outs);
    emit_outputs_v4<float><<<dim3(32, 32), 256, 0, stream>>>(
        mo, wbuf, wbuf, outs);
  }
}